// Round 1
// 70.716 us; speedup vs baseline: 1.0328x; 1.0328x over previous
//
#include <hip/hip_runtime.h>

// SoftRAMAttention — S=2048, B=64, H=8, K=12, N_POS=11
//
// addr[i,j,h] = addr_q[i,h] | addr_k[j,h] | addr_p[i-j,h]  (disjoint bit groups)
// votes[i,j]  = sum_h head_table_bit[h][addr]   (head_table is 0/1 -> bit-packed)
// out[i,:]    = max_{j<=i} votes > 0 ? table_v[:, addr_v[argmax]] : 0
//
// R6: latency attack on both kernels (theory: ~40us of the 73us is the harness
//     workspace-poison fill at HBM roofline; our kernels are the other ~30us and
//     are latency-bound, not throughput-bound).
//     - precompute: branchless (unconditional clamped token loads -> 24-deep MLP),
//       ballot-based table bit-pack (1 coalesced load/lane vs 32 serial/thread),
//       and NEW: addr_v (V16) precomputed for all (s,b) on otherwise-idle CUs.
//     - vote: explicit 8-deep register prefetch of AK16/P16 (statically indexed,
//       ~64 VGPR), __launch_bounds__(256,4) to keep 4 blocks/CU; epilogue is now
//       2 dependent loads (V16 -> table_v) instead of 12 scattered token loads.

#define SS 2048
#define BB 64
#define HH 8
#define KK 12
#define NPOS 11
#define TBL 4096           // 1 << KK
#define TBLW (TBL / 32)    // 128 words per head

typedef unsigned short u16;
typedef unsigned int u32;
typedef unsigned long long u64;

#define SEG_A (SS * HH)        // 16384: (s,h) addr triples
#define SEG_B (HH * TBL)       // 32768: one thread per table bit
#define SEG_C (SS * BB)        // 131072: addr_v entries
#define TOTAL (SEG_A + SEG_B + SEG_C)   // 180224 = 704 * 256

__global__ __launch_bounds__(256) void precompute_kernel(
    const int* __restrict__ tokens,        // (S,B) values {0,1}
    const int* __restrict__ conn_heads,    // (H,K)
    const float* __restrict__ head_table,  // (H,4096) values {0.0,1.0}
    const int* __restrict__ conn_v,        // (B,K)
    u16* __restrict__ A16, u16* __restrict__ AK16, u16* __restrict__ P16,
    u32* __restrict__ bits, u16* __restrict__ V16)
{
    const int gid = blockIdx.x * 256 + threadIdx.x;
    if (gid < SEG_A) {
        // branchless: all loads unconditional (clamped), selects via cndmask.
        const int s = gid >> 3;
        const int h = gid & 7;
        int aq = 0, ak = 0, ap = 0;
        #pragma unroll
        for (int k = 0; k < KK; ++k) {
            const int c = conn_heads[h * KK + k];
            const int sh = KK - 1 - k;
            const int cq = min(c, BB - 1);
            const int ck = min(max(c - BB, 0), BB - 1);
            const int cp = min(max(c - 2 * BB, 0), NPOS - 1);
            const int tq = tokens[s * BB + cq] & 1;
            const int tk = tokens[s * BB + ck] & 1;
            const int tp = (s >> (NPOS - 1 - cp)) & 1;
            aq |= (c < BB ? tq : 0) << sh;
            ap |= (c >= 2 * BB ? tp : 0) << sh;
            ak |= ((c >= BB) && (c < 2 * BB) ? tk : 0) << sh;
        }
        A16[gid]  = (u16)aq;
        AK16[gid] = (u16)ak;
        P16[gid]  = (u16)ap;
    } else if (gid < SEG_A + SEG_B) {
        // one thread per table bit; wave-wide ballot packs 64 bits at once.
        // segment starts at gid=16384 (wave- and block-aligned), all lanes active.
        const int t = gid - SEG_A;                 // == h*4096 + idx
        const u64 m = __ballot(head_table[t] > 0.5f);
        if ((t & 63) == 0) {
            bits[(t >> 5) + 0] = (u32)m;
            bits[(t >> 5) + 1] = (u32)(m >> 32);
        }
    } else {
        // addr_v[s][b]: moves 12 scattered loads out of every vote-block tail.
        const int t = gid - (SEG_A + SEG_B);
        const int s = t >> 6;
        const int b = t & 63;
        int av = 0;
        #pragma unroll
        for (int k = 0; k < KK; ++k) {
            av |= (tokens[s * BB + conn_v[b * KK + k]] & 1) << (KK - 1 - k);
        }
        V16[t] = (u16)av;
    }
}

// two packed 12-bit addrs per 32-bit word; heads (2w, 2w+1)
__device__ __forceinline__ int votes_packed(const u32* sbits,
                                            const uint4& q, const uint4& kk, const uint4& pp)
{
    int v = 0;
    u32 w, a0, a1;
    w = q.x | kk.x | pp.x;
    a0 = w & 0xFFFFu; a1 = w >> 16;
    v += (sbits[0 * TBLW + (a0 >> 5)] >> (a0 & 31)) & 1;
    v += (sbits[1 * TBLW + (a1 >> 5)] >> (a1 & 31)) & 1;
    w = q.y | kk.y | pp.y;
    a0 = w & 0xFFFFu; a1 = w >> 16;
    v += (sbits[2 * TBLW + (a0 >> 5)] >> (a0 & 31)) & 1;
    v += (sbits[3 * TBLW + (a1 >> 5)] >> (a1 & 31)) & 1;
    w = q.z | kk.z | pp.z;
    a0 = w & 0xFFFFu; a1 = w >> 16;
    v += (sbits[4 * TBLW + (a0 >> 5)] >> (a0 & 31)) & 1;
    v += (sbits[5 * TBLW + (a1 >> 5)] >> (a1 & 31)) & 1;
    w = q.w | kk.w | pp.w;
    a0 = w & 0xFFFFu; a1 = w >> 16;
    v += (sbits[6 * TBLW + (a0 >> 5)] >> (a0 & 31)) & 1;
    v += (sbits[7 * TBLW + (a1 >> 5)] >> (a1 & 31)) & 1;
    return v;
}

__global__ __launch_bounds__(256, 4) void vote_kernel(
    const u16* __restrict__ A16, const u16* __restrict__ AK16, const u16* __restrict__ P16,
    const u32* __restrict__ bits_g,
    const u16* __restrict__ V16,        // (S,B) precomputed addr_v
    const float* __restrict__ table_v,  // (B,4096)
    float* __restrict__ out)            // (S,B) fp32
{
    __shared__ u32 sbits[HH * TBLW];   // 4 KB
    __shared__ u32 skey[2][4];

    const int tid = threadIdx.x;
    const int b = blockIdx.x;
    const int i0 = b;             // short row (i0 <= 1023)
    const int i1 = SS - 1 - b;    // long row  (i1 >= 1024)

    ((uint4*)sbits)[tid] = ((const uint4*)bits_g)[tid];   // 256 x 16B = 4 KB
    __syncthreads();

    const uint4 q0 = *(const uint4*)(A16 + i0 * HH);
    const uint4 q1 = *(const uint4*)(A16 + i1 * HH);

    // key = (v << 12) | (4095 - j): max key == max v, tie -> smallest j.
    u32 key0 = 0u, key1 = 0u;

    // rows (i0, i1) have (i0+1) + (i1+1) = 2049 columns total.
    // flat c in [0,2048): c <= i0 -> (row i0, j=c); else (row i1, j=c-i0-1).
    // Explicit 8-deep prefetch: issue ALL 16 global loads before any LDS use,
    // statically indexed arrays so they live in VGPRs (no scratch).
    uint4 kkv[8], ppv[8];
    #pragma unroll
    for (int it = 0; it < 8; ++it) {
        const int c = (it << 8) + tid;
        const bool r0 = (c <= i0);
        const int j = r0 ? c : (c - i0 - 1);       // row-local column
        const int d = r0 ? (i0 - c) : (2048 - c);  // i - j for that row
        kkv[it] = *(const uint4*)(AK16 + j * HH);
        ppv[it] = *(const uint4*)(P16 + d * HH);
    }
    #pragma unroll
    for (int it = 0; it < 8; ++it) {
        const int c = (it << 8) + tid;
        const bool r0 = (c <= i0);
        const int j = r0 ? c : (c - i0 - 1);
        const uint4 q = r0 ? q0 : q1;
        const int v = votes_packed(sbits, q, kkv[it], ppv[it]);
        const u32 key = ((u32)v << 12) | (u32)(4095 - j);
        if (r0) { key0 = key0 > key ? key0 : key; }
        else    { key1 = key1 > key ? key1 : key; }
    }
    if (tid == 0) {   // straggler c = 2048 -> row i1, j = i1, d = 0
        const uint4 kk = *(const uint4*)(AK16 + i1 * HH);
        const uint4 pp = *(const uint4*)(P16);
        const int v = votes_packed(sbits, q1, kk, pp);
        const u32 key = ((u32)v << 12) | (u32)(4095 - i1);
        key1 = key1 > key ? key1 : key;
    }

    // 64-lane butterfly max for both rows (no barriers)
    #pragma unroll
    for (int off = 32; off > 0; off >>= 1) {
        u32 o0 = (u32)__shfl_xor((int)key0, off, 64);
        u32 o1 = (u32)__shfl_xor((int)key1, off, 64);
        key0 = key0 > o0 ? key0 : o0;
        key1 = key1 > o1 ? key1 : o1;
    }
    if ((tid & 63) == 0) {
        skey[0][tid >> 6] = key0;
        skey[1][tid >> 6] = key1;
    }
    __syncthreads();

    // threads 0..63 emit row i0, threads 64..127 emit row i1.
    // epilogue is now just 2 dependent loads: V16[best,lane] -> table_v.
    if (tid < 128) {
        const int r = tid >> 6;
        const int lane = tid & 63;
        u32 ka = skey[r][0] > skey[r][1] ? skey[r][0] : skey[r][1];
        u32 kb = skey[r][2] > skey[r][3] ? skey[r][2] : skey[r][3];
        u32 kf = ka > kb ? ka : kb;
        const int row = r ? i1 : i0;
        float o = 0.0f;
        if ((kf >> 12) > 0) {
            const int best = 4095 - (int)(kf & 4095u);
            o = table_v[lane * TBL + (int)V16[best * BB + lane]];
        }
        out[row * BB + lane] = o;
    }
}

extern "C" void kernel_launch(void* const* d_in, const int* in_sizes, int n_in,
                              void* d_out, int out_size, void* d_ws, size_t ws_size,
                              hipStream_t stream) {
    const int*   tokens     = (const int*)d_in[0];
    const int*   conn_heads = (const int*)d_in[1];
    const float* head_table = (const float*)d_in[2];
    const int*   conn_v     = (const int*)d_in[3];
    const float* table_v    = (const float*)d_in[4];
    float* out = (float*)d_out;

    char* w = (char*)d_ws;
    u16* A16  = (u16*)(w);              // 32 KB
    u16* AK16 = (u16*)(w + 32768);      // 32 KB
    u16* P16  = (u16*)(w + 65536);      // 32 KB
    u32* bits = (u32*)(w + 98304);      //  4 KB
    u16* V16  = (u16*)(w + 102400);     // 256 KB

    precompute_kernel<<<TOTAL / 256, 256, 0, stream>>>(
        tokens, conn_heads, head_table, conn_v, A16, AK16, P16, bits, V16);
    vote_kernel<<<SS / 2, 256, 0, stream>>>(
        A16, AK16, P16, bits, V16, table_v, out);
}